// Round 4
// baseline (149.936 us; speedup 1.0000x reference)
//
#include <hip/hip_runtime.h>

#define IMG 512
#define BATCH 64
#define ROWS_PER_STRIP 64
#define NSTEP 74   // 64 out rows + 10 halo rows

__global__ __launch_bounds__(256, 2) void ssim_stream_kernel(
    const float* __restrict__ img1, const float* __restrict__ img2,
    const float* __restrict__ window, float* __restrict__ partials)
{
    __shared__ float wred[4];
    const int tid   = threadIdx.x;
    const int strip = blockIdx.x;      // 0..7
    const int b     = blockIdx.y;      // batch
    const int c0    = tid * 2;         // this thread's 2 output cols
    const int r_base = strip * ROWS_PER_STRIP;

    // 1-D gaussian = row sums of the 11x11 window (rows sum to ~g[k]); force SGPR
    float gw[11];
    #pragma unroll
    for (int k = 0; k < 11; ++k) {
        float s = 0.f;
        #pragma unroll
        for (int j = 0; j < 11; ++j) s += window[k*11 + j];
        gw[k] = __int_as_float(__builtin_amdgcn_readfirstlane(__float_as_int(s)));
    }

    const float* P1 = img1 + (size_t)b * (IMG*IMG);
    const float* P2 = img2 + (size_t)b * (IMG*IMG);

    const bool edge = (c0 < 6) || (c0 > IMG - 8);   // cols c0-6 .. c0+7 OOB risk

    // 11-slot ring of vertical accumulators: 5 channels x 2 cols
    float acc[11][5][2];
    #pragma unroll
    for (int s = 0; s < 11; ++s)
        #pragma unroll
        for (int ch = 0; ch < 5; ++ch) { acc[s][ch][0] = 0.f; acc[s][ch][1] = 0.f; }

    float thr_sum = 0.f;
    const float C1 = 1e-4f, C2 = 9e-4f;

    #pragma unroll 1
    for (int jj = 0; jj < 7; ++jj) {
      #pragma unroll
      for (int u = 0; u < 11; ++u) {
        const int t = jj*11 + u;            // stream step; t mod 11 == u (compile-time slots)
        if (t < NSTEP) {
          const int rr = r_base - 5 + t;    // raw image row

          float a[14], bb[14];
          if (rr >= 0 && rr < IMG) {
            const float* r1 = P1 + (size_t)rr * IMG;
            const float* r2 = P2 + (size_t)rr * IMG;
            if (!edge) {
              #pragma unroll
              for (int q = 0; q < 7; ++q) {   // words c0-6 .. c0+7, 8B-aligned
                float2 va = *(const float2*)(r1 + c0 - 6 + 2*q);
                float2 vb = *(const float2*)(r2 + c0 - 6 + 2*q);
                a[2*q]   = va.x; a[2*q+1]  = va.y;
                bb[2*q]  = vb.x; bb[2*q+1] = vb.y;
              }
            } else {
              #pragma unroll
              for (int e = 0; e < 14; ++e) {
                int gc = c0 - 6 + e;
                bool ok = (gc >= 0) && (gc < IMG);
                a[e]  = ok ? r1[gc] : 0.f;
                bb[e] = ok ? r2[gc] : 0.f;
              }
            }
          } else {
            #pragma unroll
            for (int e = 0; e < 14; ++e) { a[e] = 0.f; bb[e] = 0.f; }
          }

          // horizontal 5-channel conv for the 2 cols.
          // col0 window = a[1..11], col1 window = a[2..12]
          float h1c0=0.f,h2c0=0.f,h11c0=0.f,h22c0=0.f,h12c0=0.f;
          float h1c1=0.f,h2c1=0.f,h11c1=0.f,h22c1=0.f,h12c1=0.f;
          #pragma unroll
          for (int t2 = 1; t2 <= 12; ++t2) {
            float av = a[t2], bv = bb[t2];
            float pa = av*av, pb = bv*bv, pab = av*bv;
            if (t2 <= 11) {
              float w = gw[t2-1];
              h1c0 += w*av; h2c0 += w*bv; h11c0 += w*pa; h22c0 += w*pb; h12c0 += w*pab;
            }
            if (t2 >= 2) {
              float w = gw[t2-2];
              h1c1 += w*av; h2c1 += w*bv; h11c1 += w*pa; h22c1 += w*pb; h12c1 += w*pab;
            }
          }

          // vertical accumulate: slot s holds local out-row l = t + ((s-u) mod 11),
          // tap index k = 10 - ((s-u) mod 11)  (all compile-time after unroll)
          #pragma unroll
          for (int s = 0; s < 11; ++s) {
            const int k = 10 - (((s - u) % 11 + 11) % 11);
            const float w = gw[k];
            acc[s][0][0] += w*h1c0;  acc[s][0][1] += w*h1c1;
            acc[s][1][0] += w*h2c0;  acc[s][1][1] += w*h2c1;
            acc[s][2][0] += w*h11c0; acc[s][2][1] += w*h11c1;
            acc[s][3][0] += w*h22c0; acc[s][3][1] += w*h22c1;
            acc[s][4][0] += w*h12c0; acc[s][4][1] += w*h12c1;
          }

          // slot u just received its last tap (out-row o = r_base - 10 + t)
          if (t >= 10) {
            #pragma unroll
            for (int cc = 0; cc < 2; ++cc) {
              float mu1 = acc[u][0][cc], mu2 = acc[u][1][cc];
              float mu1s = mu1*mu1, mu2s = mu2*mu2, mu12 = mu1*mu2;
              float s1  = acc[u][2][cc] - mu1s;
              float s2  = acc[u][3][cc] - mu2s;
              float s12 = acc[u][4][cc] - mu12;
              float num = (2.f*mu12 + C1) * (2.f*s12 + C2);
              float den = (mu1s + mu2s + C1) * (s1 + s2 + C2);
              thr_sum += num / den;
            }
          }
          #pragma unroll
          for (int ch = 0; ch < 5; ++ch) { acc[u][ch][0] = 0.f; acc[u][ch][1] = 0.f; }
        }
      }
    }

    // block reduction
    for (int d = 32; d > 0; d >>= 1) thr_sum += __shfl_down(thr_sum, d, 64);
    int wid = tid >> 6, lane = tid & 63;
    if (lane == 0) wred[wid] = thr_sum;
    __syncthreads();
    if (tid == 0) {
        float s = wred[0] + wred[1] + wred[2] + wred[3];
        partials[blockIdx.y * 8 + blockIdx.x] = s;
    }
}

__global__ __launch_bounds__(256) void ssim_reduce_kernel(
    const float* __restrict__ partials, int n, float* __restrict__ out)
{
    __shared__ double wsumd[4];
    double s = 0.0;
    for (int i = threadIdx.x; i < n; i += 256) s += (double)partials[i];
    for (int d = 32; d > 0; d >>= 1) s += __shfl_down(s, d, 64);
    int wid = threadIdx.x >> 6, lane = threadIdx.x & 63;
    if (lane == 0) wsumd[wid] = s;
    __syncthreads();
    if (threadIdx.x == 0) {
        double t = wsumd[0] + wsumd[1] + wsumd[2] + wsumd[3];
        out[0] = (float)(t / ((double)BATCH * IMG * IMG));
    }
}

extern "C" void kernel_launch(void* const* d_in, const int* in_sizes, int n_in,
                              void* d_out, int out_size, void* d_ws, size_t ws_size,
                              hipStream_t stream) {
    const float* img1   = (const float*)d_in[0];
    const float* img2   = (const float*)d_in[1];
    const float* window = (const float*)d_in[2];
    float* out = (float*)d_out;
    float* partials = (float*)d_ws;

    dim3 grid(IMG / ROWS_PER_STRIP, BATCH);   // 8 x 64 = 512 blocks
    ssim_stream_kernel<<<grid, dim3(256), 0, stream>>>(img1, img2, window, partials);

    int npart = (IMG / ROWS_PER_STRIP) * BATCH;  // 512
    ssim_reduce_kernel<<<1, 256, 0, stream>>>(partials, npart, out);
}